// Round 1
// baseline (172.940 us; speedup 1.0000x reference)
//
#include <hip/hip_runtime.h>
#include <hip/hip_bf16.h>
#include <math.h>

#define BATCH 32
#define T 1024
#define F 768

// ---------------------------------------------------------------------------
// K1: per-token stats. One wave (64 lanes) per token; block = 4 waves.
// Computes ||tok||, p = sigmoid(l1-l0), y0 = tok.fc_final_w[0], y1 = tok.fc_final_w[1]
// ---------------------------------------------------------------------------
__global__ __launch_bounds__(256) void k1_token_stats(
    const float* __restrict__ x, const float* __restrict__ fc_w,
    const float* __restrict__ fc_b, const float* __restrict__ fc_final_w,
    float* __restrict__ ws_p, float* __restrict__ ws_y0,
    float* __restrict__ ws_y1, float* __restrict__ ws_norm)
{
    const int wave = threadIdx.x >> 6;
    const int lane = threadIdx.x & 63;
    const int g = blockIdx.x * 4 + wave;          // global token id [0, 32768)
    const float* tok = x + (size_t)g * F;

    float asq = 0.f, a0 = 0.f, a1 = 0.f, af0 = 0.f, af1 = 0.f;
    #pragma unroll
    for (int j = 0; j < 3; ++j) {
        const int off = j * 256 + lane * 4;
        float4 v  = *(const float4*)(tok + off);
        float4 w0 = *(const float4*)(fc_w + off);
        float4 w1 = *(const float4*)(fc_w + F + off);
        float4 f0 = *(const float4*)(fc_final_w + off);
        float4 f1 = *(const float4*)(fc_final_w + F + off);
        asq += v.x*v.x  + v.y*v.y  + v.z*v.z  + v.w*v.w;
        a0  += v.x*w0.x + v.y*w0.y + v.z*w0.z + v.w*w0.w;
        a1  += v.x*w1.x + v.y*w1.y + v.z*w1.z + v.w*w1.w;
        af0 += v.x*f0.x + v.y*f0.y + v.z*f0.z + v.w*f0.w;
        af1 += v.x*f1.x + v.y*f1.y + v.z*f1.z + v.w*f1.w;
    }
    #pragma unroll
    for (int d = 32; d > 0; d >>= 1) {
        asq += __shfl_xor(asq, d);
        a0  += __shfl_xor(a0,  d);
        a1  += __shfl_xor(a1,  d);
        af0 += __shfl_xor(af0, d);
        af1 += __shfl_xor(af1, d);
    }
    if (lane == 0) {
        const float l0 = a0 + fc_b[0];
        const float l1 = a1 + fc_b[1];
        ws_p[g]    = 1.f / (1.f + expf(l0 - l1));   // softmax(...)[1]
        ws_y0[g]   = af0;
        ws_y1[g]   = af1;
        ws_norm[g] = sqrtf(asq);
    }
}

// ---------------------------------------------------------------------------
// K2: per-batch argmax of p (numpy tie-break: first index)
// ---------------------------------------------------------------------------
__global__ __launch_bounds__(256) void k2_argmax(
    const float* __restrict__ ws_p, int* __restrict__ ws_idx)
{
    const int b = blockIdx.x;
    __shared__ float sv[256];
    __shared__ int   si[256];
    float best = -1e30f; int bi = 0;
    for (int t = threadIdx.x; t < T; t += 256) {
        const float p = ws_p[b * T + t];
        if (p > best) { best = p; bi = t; }
    }
    sv[threadIdx.x] = best; si[threadIdx.x] = bi;
    __syncthreads();
    for (int s = 128; s > 0; s >>= 1) {
        if (threadIdx.x < s) {
            const float o = sv[threadIdx.x + s];
            const int  oi = si[threadIdx.x + s];
            if (o > sv[threadIdx.x] ||
                (o == sv[threadIdx.x] && oi < si[threadIdx.x])) {
                sv[threadIdx.x] = o; si[threadIdx.x] = oi;
            }
        }
        __syncthreads();
    }
    if (threadIdx.x == 0) ws_idx[b] = si[0];
}

// ---------------------------------------------------------------------------
// K3: per-(batch, segment) partial online-softmax-weighted accumulation.
// grid = (S=64 segments, B=32). 16 tokens/block, 1 wave per token per iter.
// partial = (m, den, num0, num1) with den = sum exp(s-m)*p, num_c = ..*y_c
// ---------------------------------------------------------------------------
__global__ __launch_bounds__(256) void k3_attn_row(
    const float* __restrict__ x, const float* __restrict__ ws_p,
    const float* __restrict__ ws_y0, const float* __restrict__ ws_y1,
    const float* __restrict__ ws_norm, const int* __restrict__ ws_idx,
    float* __restrict__ ws_part)
{
    const int seg  = blockIdx.x;
    const int b    = blockIdx.y;
    const int wave = threadIdx.x >> 6;
    const int lane = threadIdx.x & 63;

    __shared__ float q[F];
    __shared__ float red[4][4];

    const int idx = ws_idx[b];
    const float* qg = x + ((size_t)b * T + idx) * F;
    for (int i = threadIdx.x; i < F; i += 256) q[i] = qg[i];
    __syncthreads();

    const float nq = ws_norm[b * T + idx];

    float m = -1e30f, den = 0.f, n0 = 0.f, n1 = 0.f;
    #pragma unroll
    for (int it = 0; it < 4; ++it) {
        const int t = seg * 16 + it * 4 + wave;
        const float* tok = x + ((size_t)b * T + t) * F;
        float acc = 0.f;
        #pragma unroll
        for (int j = 0; j < 3; ++j) {
            const int off = j * 256 + lane * 4;
            float4 v  = *(const float4*)(tok + off);
            float4 qq = *(const float4*)(&q[off]);
            acc += v.x*qq.x + v.y*qq.y + v.z*qq.z + v.w*qq.w;
        }
        #pragma unroll
        for (int d = 32; d > 0; d >>= 1) acc += __shfl_xor(acc, d);

        const float s  = acc / (nq * ws_norm[b * T + t]);
        const float p  = ws_p[b * T + t];
        const float y0 = ws_y0[b * T + t];
        const float y1 = ws_y1[b * T + t];
        if (s > m) {                       // rescale running state
            const float r = expf(m - s);   // exp(-inf)=0 handles first iter
            den *= r; n0 *= r; n1 *= r; m = s;
        }
        const float w = expf(s - m) * p;
        den += w; n0 += w * y0; n1 += w * y1;
    }
    if (lane == 0) {
        red[wave][0] = m; red[wave][1] = den; red[wave][2] = n0; red[wave][3] = n1;
    }
    __syncthreads();
    if (threadIdx.x == 0) {
        float M = red[0][0];
        for (int w = 1; w < 4; ++w) M = fmaxf(M, red[w][0]);
        float D = 0.f, N0 = 0.f, N1 = 0.f;
        for (int w = 0; w < 4; ++w) {
            const float r = expf(red[w][0] - M);
            D += red[w][1] * r; N0 += red[w][2] * r; N1 += red[w][3] * r;
        }
        float* o = ws_part + ((size_t)b * 64 + seg) * 4;
        o[0] = M; o[1] = D; o[2] = N0; o[3] = N1;
    }
}

// ---------------------------------------------------------------------------
// K4: combine 64 segment partials per batch (one wave per batch) -> out[B,2]
// ---------------------------------------------------------------------------
__global__ __launch_bounds__(64) void k4_finalize(
    const float* __restrict__ ws_part, const float* __restrict__ fc_final_b,
    float* __restrict__ out)
{
    const int b = blockIdx.x;
    const int lane = threadIdx.x;
    const float* pp = ws_part + ((size_t)b * 64 + lane) * 4;
    float m = pp[0], den = pp[1], n0 = pp[2], n1 = pp[3];
    #pragma unroll
    for (int d = 32; d > 0; d >>= 1) {
        const float om = __shfl_xor(m, d);
        const float od = __shfl_xor(den, d);
        const float o0 = __shfl_xor(n0, d);
        const float o1 = __shfl_xor(n1, d);
        const float M  = fmaxf(m, om);
        const float ra = expf(m - M), rb = expf(om - M);
        den = den * ra + od * rb;
        n0  = n0  * ra + o0 * rb;
        n1  = n1  * ra + o1 * rb;
        m = M;
    }
    if (lane == 0) {
        out[b * 2 + 0] = n0 / den + fc_final_b[0];
        out[b * 2 + 1] = n1 / den + fc_final_b[1];
    }
}

extern "C" void kernel_launch(void* const* d_in, const int* in_sizes, int n_in,
                              void* d_out, int out_size, void* d_ws, size_t ws_size,
                              hipStream_t stream) {
    const float* x          = (const float*)d_in[0];
    const float* fc_w       = (const float*)d_in[1];
    const float* fc_b       = (const float*)d_in[2];
    const float* fc_final_w = (const float*)d_in[3];
    const float* fc_final_b = (const float*)d_in[4];
    float* out = (float*)d_out;

    float* ws      = (float*)d_ws;
    float* ws_p    = ws;                      // 32768 floats
    float* ws_y0   = ws + 32768;              // 32768
    float* ws_y1   = ws + 65536;              // 32768
    float* ws_norm = ws + 98304;              // 32768
    int*   ws_idx  = (int*)(ws + 131072);     // 32 ints
    float* ws_part = ws + 131072 + 64;        // 32*64*4 = 8192 floats

    k1_token_stats<<<dim3((BATCH * T) / 4), 256, 0, stream>>>(
        x, fc_w, fc_b, fc_final_w, ws_p, ws_y0, ws_y1, ws_norm);
    k2_argmax<<<dim3(BATCH), 256, 0, stream>>>(ws_p, ws_idx);
    k3_attn_row<<<dim3(64, BATCH), 256, 0, stream>>>(
        x, ws_p, ws_y0, ws_y1, ws_norm, ws_idx, ws_part);
    k4_finalize<<<dim3(BATCH), 64, 0, stream>>>(ws_part, fc_final_b, out);
}